// Round 2
// baseline (669.266 us; speedup 1.0000x reference)
//
#include <hip/hip_runtime.h>
#include <hip/hip_bf16.h>

// WinMSA fused kernel for MI355X (gfx950), v2.
// B=64, WN=64 windows, S=49 (pad 64), C=192, H=6, D=32.
// One block per window, 1024 threads (16 waves), 2 barriers per block.
// Weights + X read direct from global (L1/L2); only QKV/P/bias live in LDS.

typedef __attribute__((ext_vector_type(4))) float f32x4;
typedef __attribute__((ext_vector_type(8))) short bf16x8;
typedef __attribute__((ext_vector_type(4))) unsigned short u16x4;

#define SCALE 0.17677669529663689f  // 32^-0.5

__device__ __forceinline__ unsigned short f2bf(float f) {
  union { float f; unsigned int u; } v; v.f = f;
  return (unsigned short)((v.u + 0x7FFFu + ((v.u >> 16) & 1u)) >> 16);  // RNE
}

// Pre-kernel: transpose weights to bf16 [out][in] for k-contiguous B-fragments.
__global__ void wprep(const float* __restrict__ Wqkv, const float* __restrict__ Wo,
                      unsigned short* __restrict__ WqkvT, unsigned short* __restrict__ WoT) {
  int i = blockIdx.x * 256 + threadIdx.x;
  if (i < 576 * 192) { int n = i / 192, k = i % 192; WqkvT[i] = f2bf(Wqkv[k * 576 + n]); }
  if (i < 192 * 192) { int n = i / 192, k = i % 192; WoT[i]   = f2bf(Wo[k * 192 + n]); }
}

__global__ __launch_bounds__(1024, 4)
void winmsa(const float* __restrict__ X, const unsigned short* __restrict__ WqkvT,
            const float* __restrict__ bqkv, const unsigned short* __restrict__ WoT,
            const float* __restrict__ bo, const float* __restrict__ btab,
            float* __restrict__ out) {
  // Row stride 200 ushorts; col bit3 XOR-swizzled by row bit3 to break scatter conflicts.
  __shared__ __align__(16) unsigned short Qs[64 * 200];   // Q, then attn-out overlay
  __shared__ __align__(16) unsigned short Ks[64 * 200];
  __shared__ __align__(16) unsigned short Vt[192 * 72];   // V transposed [d][token]
  __shared__ __align__(16) unsigned short Pb[16 * 1152];  // per-wave P [16 q][72 k]
  __shared__ float biasF[1014];

  const int tid  = threadIdx.x;
  const int w16  = tid >> 6;      // wave 0..15
  const int lane = tid & 63;
  const int g    = lane >> 4;     // 0..3
  const int c    = lane & 15;     // 0..15
  const int mt   = w16 & 3;       // query-row tile (consistent across phases)
  const int nq   = w16 >> 2;      // 16-col slice within 64-col groups
  const int wb   = blockIdx.x;

  const int wswz = ((g >> 1) & 1) << 3;  // write-side swizzle: rows rb=mt*16+4g+r -> (row>>3)&1 = (g>>1)&1
  const int rswz = ((c >> 3) & 1) << 3;  // read-side swizzle: rows 16t+c / mt*16+c -> (c>>3)&1

  for (int j = tid; j < 1014; j += 1024) biasF[j] = btab[j];

  // ---- Phase A: QKV = X @ Wqkv + b. A-frags in registers, B-frags from global. No barriers. ----
  bf16x8 afr[6];
  {
    const int row = mt * 16 + c;
    const float* xr = X + (size_t)wb * 9408 + row * 192;
    #pragma unroll
    for (int ks = 0; ks < 6; ++ks) {
      bf16x8 a = {0, 0, 0, 0, 0, 0, 0, 0};
      if (row < 49) {  // rows 49..63 are zero-pad (and would be OOB for the last window)
        f32x4 lo = *(const f32x4*)(xr + ks * 32 + g * 8);
        f32x4 hi = *(const f32x4*)(xr + ks * 32 + g * 8 + 4);
        a[0] = (short)f2bf(lo[0]); a[1] = (short)f2bf(lo[1]);
        a[2] = (short)f2bf(lo[2]); a[3] = (short)f2bf(lo[3]);
        a[4] = (short)f2bf(hi[0]); a[5] = (short)f2bf(hi[1]);
        a[6] = (short)f2bf(hi[2]); a[7] = (short)f2bf(hi[3]);
      }
      afr[ks] = a;
    }
  }

  #pragma unroll
  for (int j = 0; j < 9; ++j) {  // 9 col-tiles of 16: j<3 -> Q, j<6 -> K, else V
    const unsigned short* wp = WqkvT + j * 12288 + (nq * 16 + c) * 192 + g * 8;
    f32x4 acc = {0.f, 0.f, 0.f, 0.f};
    #pragma unroll
    for (int ks = 0; ks < 6; ++ks)
      acc = __builtin_amdgcn_mfma_f32_16x16x32_bf16(afr[ks], *(const bf16x8*)(wp + ks * 32), acc, 0, 0, 0);
    const int col = j * 64 + nq * 16 + c;   // 0..575
    const float bias = bqkv[col];
    const int rb = mt * 16 + g * 4;
    if (j < 3) {
      const int csw = col ^ wswz;
      #pragma unroll
      for (int r = 0; r < 4; ++r) Qs[(rb + r) * 200 + csw] = f2bf(acc[r] + bias);
    } else if (j < 6) {
      const int csw = (col - 192) ^ wswz;
      #pragma unroll
      for (int r = 0; r < 4; ++r) Ks[(rb + r) * 200 + csw] = f2bf(acc[r] + bias);
    } else {
      u16x4 pv;
      #pragma unroll
      for (int r = 0; r < 4; ++r) pv[r] = f2bf(acc[r] + bias);
      *(u16x4*)(Vt + (col - 384) * 72 + rb) = pv;  // 4 consecutive tokens
    }
  }
  __syncthreads();  // barrier 1: Q/K/V + bias table ready

  // ---- Phase B: swapped QK^T. Lane (g,c) holds S^T[k=16t+4g+r][q=mt*16+c]. ----
  const int qbase = mt * 16;
  const int q = qbase + c;
  const bool qvalid = q < 49;
  const int qq = qvalid ? q : 48;
  const int qoff6 = ((6 - qq / 7) * 13 + (6 - qq % 7)) * 6;
  int kb6[16];                       // per-lane bias base, hoisted out of the head loop
  #pragma unroll
  for (int i = 0; i < 16; ++i) {
    int k = (i >> 2) * 16 + g * 4 + (i & 3);
    int kk = k < 49 ? k : 48;        // clamp -> idx always within [0,1014)
    kb6[i] = ((kk / 7) * 13 + (kk % 7)) * 6;
  }
  unsigned short* Pw = Pb + w16 * 1152;
  const f32x4 z = {0.f, 0.f, 0.f, 0.f};

  auto attn_task = [&](int h) {
    const int cofs = (h * 32 + g * 8) ^ rswz;
    const bf16x8 bq = *(const bf16x8*)(Qs + (qbase + c) * 200 + cofs);
    f32x4 s[4];
    #pragma unroll
    for (int t = 0; t < 4; ++t)
      s[t] = __builtin_amdgcn_mfma_f32_16x16x32_bf16(
          *(const bf16x8*)(Ks + (t * 16 + c) * 200 + cofs), bq, z, 0, 0, 0);

    float p[16];
    float mx = -3e38f;
    #pragma unroll
    for (int i = 0; i < 16; ++i) {
      const int t = i >> 2, r = i & 3;
      const int k = t * 16 + g * 4 + r;
      const float b = biasF[kb6[i] + qoff6 + h];
      const float lg = (qvalid && (k < 49)) ? fmaf(s[t][r], SCALE, b) : -1e30f;
      p[i] = lg;
      mx = fmaxf(mx, lg);
    }
    mx = fmaxf(mx, __shfl_xor(mx, 16));
    mx = fmaxf(mx, __shfl_xor(mx, 32));   // full k-row max for query q
    float sum = 0.f;
    #pragma unroll
    for (int i = 0; i < 16; ++i) { p[i] = __expf(p[i] - mx); sum += p[i]; }
    sum += __shfl_xor(sum, 16);
    sum += __shfl_xor(sum, 32);
    const float inv = 1.0f / sum;
    #pragma unroll
    for (int t = 0; t < 4; ++t) {        // k = 16t+4g+{0..3} consecutive -> b64 write
      u16x4 pk;
      #pragma unroll
      for (int r = 0; r < 4; ++r) pk[r] = f2bf(p[t * 4 + r] * inv);
      *(u16x4*)(Pw + c * 72 + t * 16 + g * 4) = pk;
    }

    // PV: A = P[q][k] (wave-private, ds-ordered), B = Vt[d][token]
    f32x4 o0 = z, o1 = z;
    #pragma unroll
    for (int ks = 0; ks < 2; ++ks) {
      const bf16x8 ap = *(const bf16x8*)(Pw + c * 72 + ks * 32 + g * 8);
      const bf16x8 v0 = *(const bf16x8*)(Vt + (h * 32 + c) * 72 + ks * 32 + g * 8);
      const bf16x8 v1 = *(const bf16x8*)(Vt + (h * 32 + 16 + c) * 72 + ks * 32 + g * 8);
      o0 = __builtin_amdgcn_mfma_f32_16x16x32_bf16(ap, v0, o0, 0, 0, 0);
      o1 = __builtin_amdgcn_mfma_f32_16x16x32_bf16(ap, v1, o1, 0, 0, 0);
    }
    const int rb = qbase + g * 4;
    #pragma unroll
    for (int r = 0; r < 4; ++r) {        // attn-out overlays Q (own cell read-then-written by same wave)
      Qs[(rb + r) * 200 + ((h * 32 + c) ^ wswz)]      = f2bf(o0[r]);
      Qs[(rb + r) * 200 + ((h * 32 + 16 + c) ^ wswz)] = f2bf(o1[r]);
    }
  };

  attn_task(w16 >> 2);                      // tasks (mt, h=0..3), all 16 waves
  if (w16 < 8) attn_task(4 + (w16 >> 2));   // tasks (mt, h=4..5), waves 0..7
  __syncthreads();  // barrier 2: attn-out complete

  // ---- Phase C: Y = attnout @ Wo + bo. A-frags hoisted, B-frags from global. ----
  bf16x8 ofr[6];
  #pragma unroll
  for (int ks = 0; ks < 6; ++ks)
    ofr[ks] = *(const bf16x8*)(Qs + (mt * 16 + c) * 200 + ((ks * 32 + g * 8) ^ rswz));
  float* og = out + (size_t)wb * 9408;
  #pragma unroll
  for (int jj = 0; jj < 3; ++jj) {
    const int col = jj * 64 + nq * 16 + c;
    const unsigned short* wp = WoT + col * 192 + g * 8;
    f32x4 acc = {0.f, 0.f, 0.f, 0.f};
    #pragma unroll
    for (int ks = 0; ks < 6; ++ks)
      acc = __builtin_amdgcn_mfma_f32_16x16x32_bf16(ofr[ks], *(const bf16x8*)(wp + ks * 32), acc, 0, 0, 0);
    const float bb = bo[col];
    #pragma unroll
    for (int r = 0; r < 4; ++r) {
      const int row = mt * 16 + g * 4 + r;
      if (row < 49) og[row * 192 + col] = acc[r] + bb;
    }
  }
}

extern "C" void kernel_launch(void* const* d_in, const int* in_sizes, int n_in,
                              void* d_out, int out_size, void* d_ws, size_t ws_size,
                              hipStream_t stream) {
  const float* X    = (const float*)d_in[0];
  const float* Wqkv = (const float*)d_in[1];
  const float* bqkv = (const float*)d_in[2];
  const float* Wo   = (const float*)d_in[3];
  const float* bo   = (const float*)d_in[4];
  const float* btab = (const float*)d_in[5];

  unsigned short* WqkvT = (unsigned short*)d_ws;        // 576*192 bf16
  unsigned short* WoT   = WqkvT + 576 * 192;            // 192*192 bf16

  wprep<<<432, 256, 0, stream>>>(Wqkv, Wo, WqkvT, WoT);
  winmsa<<<4096, 1024, 0, stream>>>(X, WqkvT, bqkv, WoT, bo, btab, (float*)d_out);
}